// Round 8
// baseline (805.432 us; speedup 1.0000x reference)
//
#include <hip/hip_runtime.h>
#include <math.h>

typedef float v4f __attribute__((ext_vector_type(4)));

#define NCOL4  28672       // W_proj row length in float4 (114688/4)
#define LAYER4 287744      // floats-per-layer / 4 (1150976/4) = 281*1024

// Amplification factors (DIAGNOSTIC ROUND: each kernel repeats its body N
// times with identical idempotent writes so every kernel exceeds the 170 µs
// harness fills and surfaces in rocprof top-5 with its own counters).
#define REP_GEMV 6
#define REP_DEC  24
#define REP_SCAT 5

// ws layout (floats)
#define OFF_PE   0                       // pe: 448 rows x 512
#define OFF_ROWS (448 * 512)             // rows: 896 x 1024
// total: 1,146,880 floats = 4.6 MB

__device__ __forceinline__ float gelu_erf(float x) {
    return 0.5f * x * (1.0f + erff(x * 0.70710678118654752440f));
}

// K1 (round-6 structure): pe[(p*2+b)][512] = cond[b] @ W slice + bproj slice.
// 224 blocks, 512 threads, k-split 4 in-block.
__global__ __launch_bounds__(512) void k_gemv(const float* __restrict__ cond,
                                              const float* __restrict__ W,
                                              const float* __restrict__ bproj,
                                              float* __restrict__ pe) {
    const int tid = threadIdx.x;
    const int p   = blockIdx.x;          // [0,224)

    __shared__ float cs[768];
    __shared__ v4f   red[1024];

    cs[tid] = cond[tid];
    if (tid < 256) cs[512 + tid] = cond[512 + tid];
    __syncthreads();

    const int kres = tid >> 7;           // 0..3
    const int c4   = tid & 127;
    const v4f* __restrict__ Wp4 = (const v4f*)W + (size_t)kres * NCOL4 + (size_t)p * 128 + c4;

    for (int rep = 0; rep < REP_GEMV; ++rep) {
        asm volatile("" ::: "memory");   // block LICM across reps
        v4f a0 = {0.f, 0.f, 0.f, 0.f};
        v4f a1 = {0.f, 0.f, 0.f, 0.f};
#pragma unroll 4
        for (int i = 0; i < 96; ++i) {   // k = 4*i + kres
            v4f w = Wp4[(size_t)i * (4 * NCOL4)];
            a0 += w * cs[4 * i + kres];
            a1 += w * cs[384 + 4 * i + kres];
        }
        red[tid]       = a0;
        red[512 + tid] = a1;
        __syncthreads();
        if (tid < 256) {
            const int b = tid >> 7;
            const int c = tid & 127;
            const int o = b * 512 + c;
            v4f s = red[o] + red[o + 128] + red[o + 256] + red[o + 384];
            s += ((const v4f*)bproj)[(size_t)p * 128 + c];
            ((v4f*)pe)[((size_t)p * 2 + b) * 128 + c] = s;
        }
        __syncthreads();
    }
}

// K2 (round-6 structure): dec1+dec2 for 4 pe-rows, one path per block.
__global__ __launch_bounds__(512) void k_dec(const float* __restrict__ pe,
                                             const float* __restrict__ WA1,
                                             const float* __restrict__ bA1,
                                             const float* __restrict__ WA2,
                                             const float* __restrict__ bA2,
                                             const float* __restrict__ WB1,
                                             const float* __restrict__ bB1,
                                             const float* __restrict__ WB2,
                                             const float* __restrict__ bB2,
                                             const float* __restrict__ scales,
                                             float* __restrict__ rows) {
    const int tid  = threadIdx.x;
    const int pp   = blockIdx.x;         // [0,112)
    const int path = blockIdx.y;         // 0=A, 1=B

    __shared__ float pe_s[4][512];
    __shared__ float h_s[4][256];

    ((v4f*)pe_s)[tid] = ((const v4f*)pe)[(size_t)pp * 512 + tid];
    __syncthreads();

    const float* __restrict__ W1 = path ? WB1 : WA1;
    const float* __restrict__ b1 = path ? bB1 : bA1;

    for (int rep = 0; rep < REP_DEC; ++rep) {
        asm volatile("" ::: "memory");
        {
            const int half = tid >> 8;
            const int j    = tid & 255;
            float a0 = 0.f, a1 = 0.f;
#pragma unroll 8
            for (int k = 0; k < 512; ++k) {
                float w = W1[k * 256 + j];
                a0 = fmaf(pe_s[2 * half][k], w, a0);
                a1 = fmaf(pe_s[2 * half + 1][k], w, a1);
            }
            float bb = b1[j];
            h_s[2 * half][j]     = gelu_erf(a0 + bb);
            h_s[2 * half + 1][j] = gelu_erf(a1 + bb);
        }
        __syncthreads();
        {
            const int half = tid >> 8;
            const int j4   = tid & 255;
            const int p    = 2 * pp + half;
            const v4f* __restrict__ W2 = (const v4f*)(path ? WB2 : WA2);
            const v4f  b2 = ((const v4f*)(path ? bB2 : bA2))[j4];
            const float sc = scales[p * 2 + path];
            v4f a0 = {0.f, 0.f, 0.f, 0.f};
            v4f a1 = {0.f, 0.f, 0.f, 0.f};
#pragma unroll 4
            for (int k = 0; k < 256; ++k) {
                v4f w = W2[k * 256 + j4];
                a0 += h_s[2 * half][k] * w;
                a1 += h_s[2 * half + 1][k] * w;
            }
            v4f* __restrict__ rows4 = (v4f*)rows;
            const size_t rho0 = (size_t)(p * 2) * 2 + path;
            rows4[(rho0)     * 256 + j4] = (a0 + b2) * sc;
            rows4[(rho0 + 2) * 256 + j4] = (a1 + b2) * sc;
        }
        __syncthreads();   // h_s rewritten next rep
    }
}

// K3 (round-6 structure): balanced scatter, nt stores.
__global__ __launch_bounds__(512) void k_scatter(const float* __restrict__ rows,
                                                 float* __restrict__ out) {
    const int yl = blockIdx.y;
    const int b  = yl >> 5;
    const int l  = yl & 31;
    const v4f* __restrict__ rows4 = (const v4f*)rows;
    v4f* __restrict__ out4 = (v4f*)out + (size_t)b * 9207808u + (size_t)l * LAYER4;

    const int f0 = blockIdx.x * 1024 + threadIdx.x;
    for (int rep = 0; rep < REP_SCAT; ++rep) {
        asm volatile("" ::: "memory");
#pragma unroll
        for (int u = 0; u < 2; ++u) {
            const int f = f0 + u * 512;
            int t, tstart, Asz = 16384;
            if (f < 106496) {
                if (f < 53248) { if (f < 32768) { t = 0; tstart = 0; }
                                 else           { t = 1; tstart = 32768; } }
                else           { if (f < 73728) { t = 2; tstart = 53248; }
                                 else           { t = 3; tstart = 73728; } }
            } else {
                if (f < 227328) { if (f < 166912) { t = 4; tstart = 106496; }
                                  else            { t = 5; tstart = 166912; } }
                else            { t = 6; tstart = 227328; Asz = 44032; }
            }
            const int local = f - tstart;
            const int p = l * 7 + t;
            const v4f* __restrict__ Arow = rows4 + ((size_t)(p * 2 + b) * 2) * 256;
            v4f v;
            if (local < Asz) {
                int r = (t == 6) ? (int)(((unsigned)(local >> 6) * 1525u) >> 16)
                                 : (local >> 10);
                v = Arow[(r << 4) | (local & 15)];
            } else {
                int g = local - Asz;
                v = Arow[256 + ((((g >> 2) & 63) << 2) | (g & 3))];
            }
            __builtin_nontemporal_store(v, &out4[f]);
        }
    }
}

extern "C" void kernel_launch(void* const* d_in, const int* in_sizes, int n_in,
                              void* d_out, int out_size, void* d_ws, size_t ws_size,
                              hipStream_t stream) {
    const float* cond   = (const float*)d_in[0];
    const float* Wp     = (const float*)d_in[1];
    const float* bproj  = (const float*)d_in[2];
    const float* WA1    = (const float*)d_in[3];
    const float* bA1    = (const float*)d_in[4];
    const float* WA2    = (const float*)d_in[5];
    const float* bA2    = (const float*)d_in[6];
    const float* WB1    = (const float*)d_in[7];
    const float* bB1    = (const float*)d_in[8];
    const float* WB2    = (const float*)d_in[9];
    const float* bB2    = (const float*)d_in[10];
    const float* scales = (const float*)d_in[11];
    float* out = (float*)d_out;
    float* ws  = (float*)d_ws;

    float* pe   = ws + OFF_PE;
    float* rows = ws + OFF_ROWS;

    hipLaunchKernelGGL(k_gemv,    dim3(224),     dim3(512), 0, stream, cond, Wp, bproj, pe);
    hipLaunchKernelGGL(k_dec,     dim3(112, 2),  dim3(512), 0, stream,
                       pe, WA1, bA1, WA2, bA2, WB1, bB1, WB2, bB2, scales, rows);
    hipLaunchKernelGGL(k_scatter, dim3(281, 64), dim3(512), 0, stream, rows, out);
}

// Round 9
// 106.807 us; speedup vs baseline: 7.5410x; 7.5410x over previous
//
#include <hip/hip_runtime.h>
#include <math.h>

typedef float v4f __attribute__((ext_vector_type(4)));

#define NCOL4  28672       // W_proj row length in float4 (114688/4)
#define LAYER4 287744      // floats-per-layer / 4 (1150976/4) = 281*1024

// ws layout (floats)
#define OFF_PE   0                       // pe: 448 rows x 512
#define OFF_ROWS (448 * 512)             // rows: 896 x 1024
// total: 1,146,880 floats = 4.6 MB

__device__ __forceinline__ float gelu_erf(float x) {
    return 0.5f * x * (1.0f + erff(x * 0.70710678118654752440f));
}

// K1 (round-6, unchanged): pe[(p*2+b)][512] = cond[b] @ W slice + bproj slice.
// 224 blocks, 512 threads, k-split 4 in-block. Reads W exactly once.
__global__ __launch_bounds__(512) void k_gemv(const float* __restrict__ cond,
                                              const float* __restrict__ W,
                                              const float* __restrict__ bproj,
                                              float* __restrict__ pe) {
    const int tid = threadIdx.x;
    const int p   = blockIdx.x;          // [0,224)

    __shared__ float cs[768];
    __shared__ v4f   red[1024];

    cs[tid] = cond[tid];
    if (tid < 256) cs[512 + tid] = cond[512 + tid];
    __syncthreads();

    const int kres = tid >> 7;           // 0..3
    const int c4   = tid & 127;
    const v4f* __restrict__ Wp4 = (const v4f*)W + (size_t)kres * NCOL4 + (size_t)p * 128 + c4;
    v4f a0 = {0.f, 0.f, 0.f, 0.f};
    v4f a1 = {0.f, 0.f, 0.f, 0.f};
#pragma unroll 4
    for (int i = 0; i < 96; ++i) {       // k = 4*i + kres
        v4f w = Wp4[(size_t)i * (4 * NCOL4)];
        a0 += w * cs[4 * i + kres];
        a1 += w * cs[384 + 4 * i + kres];
    }
    red[tid]       = a0;
    red[512 + tid] = a1;
    __syncthreads();
    if (tid < 256) {
        const int b = tid >> 7;
        const int c = tid & 127;
        const int o = b * 512 + c;
        v4f s = red[o] + red[o + 128] + red[o + 256] + red[o + 384];
        s += ((const v4f*)bproj)[(size_t)p * 128 + c];
        ((v4f*)pe)[((size_t)p * 2 + b) * 128 + c] = s;
    }
}

// K2 (RESTRUCTURED): dec1+dec2 for 4 pe-rows, one path per block, grid (112,2).
// Every weight element loaded ONCE per block, reused for all 4 rows.
// In-block k-split 2: thread = (column, k-half); LDS reduce between halves.
// L2 traffic: 112 MB (W1) + 224 MB (W2), was 672 MB.
__global__ __launch_bounds__(512) void k_dec(const float* __restrict__ pe,
                                             const float* __restrict__ WA1,
                                             const float* __restrict__ bA1,
                                             const float* __restrict__ WA2,
                                             const float* __restrict__ bA2,
                                             const float* __restrict__ WB1,
                                             const float* __restrict__ bB1,
                                             const float* __restrict__ WB2,
                                             const float* __restrict__ bB2,
                                             const float* __restrict__ scales,
                                             float* __restrict__ rows) {
    const int tid  = threadIdx.x;
    const int pp   = blockIdx.x;         // [0,112)
    const int path = blockIdx.y;         // 0=A, 1=B

    __shared__ float pe_s[4][512];       // 8 KB; rows r = (p_half<<1)|b
    __shared__ float part1[2][4][256];   // 8 KB
    __shared__ float h_s[4][256];        // 4 KB
    __shared__ v4f   part2[2][4][256];   // 32 KB

    ((v4f*)pe_s)[tid] = ((const v4f*)pe)[(size_t)pp * 512 + tid];
    __syncthreads();

    // dec1 partials: thread (j = tid&255, ks = tid>>8) covers k in ks-half.
    {
        const int j  = tid & 255;
        const int ks = tid >> 8;
        const float* __restrict__ W1 = path ? WB1 : WA1;
        const float* __restrict__ W1p = W1 + (size_t)(ks * 256) * 256 + j;
        const float* __restrict__ p0 = pe_s[0] + ks * 256;
        const float* __restrict__ p1 = pe_s[1] + ks * 256;
        const float* __restrict__ p2 = pe_s[2] + ks * 256;
        const float* __restrict__ p3 = pe_s[3] + ks * 256;
        float a0 = 0.f, a1 = 0.f, a2 = 0.f, a3 = 0.f;
#pragma unroll 8
        for (int kk = 0; kk < 256; ++kk) {
            float w = W1p[(size_t)kk * 256];
            a0 = fmaf(p0[kk], w, a0);
            a1 = fmaf(p1[kk], w, a1);
            a2 = fmaf(p2[kk], w, a2);
            a3 = fmaf(p3[kk], w, a3);
        }
        part1[ks][0][j] = a0; part1[ks][1][j] = a1;
        part1[ks][2][j] = a2; part1[ks][3][j] = a3;
    }
    __syncthreads();
    if (tid < 256) {
        const float* __restrict__ b1 = path ? bB1 : bA1;
        float bb = b1[tid];
#pragma unroll
        for (int r = 0; r < 4; ++r)
            h_s[r][tid] = gelu_erf(part1[0][r][tid] + part1[1][r][tid] + bb);
    }
    __syncthreads();

    // dec2 partials: thread (j4 = tid&255, ks = tid>>8) covers k in ks-half.
    {
        const int j4 = tid & 255;
        const int ks = tid >> 8;
        const v4f* __restrict__ W2v =
            (const v4f*)(path ? WB2 : WA2) + (size_t)(ks * 128) * 256 + j4;
        const float* __restrict__ h0 = h_s[0] + ks * 128;
        const float* __restrict__ h1 = h_s[1] + ks * 128;
        const float* __restrict__ h2 = h_s[2] + ks * 128;
        const float* __restrict__ h3 = h_s[3] + ks * 128;
        v4f c0 = {0.f, 0.f, 0.f, 0.f}, c1 = c0, c2 = c0, c3 = c0;
#pragma unroll 4
        for (int kk = 0; kk < 128; ++kk) {
            v4f w = W2v[(size_t)kk * 256];
            c0 += h0[kk] * w;
            c1 += h1[kk] * w;
            c2 += h2[kk] * w;
            c3 += h3[kk] * w;
        }
        part2[ks][0][j4] = c0; part2[ks][1][j4] = c1;
        part2[ks][2][j4] = c2; part2[ks][3][j4] = c3;
    }
    __syncthreads();
    if (tid < 256) {
        const int j4 = tid;
        const v4f b2v = ((const v4f*)(path ? bB2 : bA2))[j4];
        v4f* __restrict__ rows4 = (v4f*)rows;
#pragma unroll
        for (int r = 0; r < 4; ++r) {
            const int p = 2 * pp + (r >> 1);
            const int b = r & 1;
            const float sc = scales[p * 2 + path];
            const size_t rho = (size_t)(p * 2 + b) * 2 + path;
            rows4[rho * 256 + j4] = (part2[0][r][j4] + part2[1][r][j4] + b2v) * sc;
        }
    }
}

// K3 (round-6, unchanged): balanced scatter, nt stores.
__global__ __launch_bounds__(512) void k_scatter(const float* __restrict__ rows,
                                                 float* __restrict__ out) {
    const int yl = blockIdx.y;
    const int b  = yl >> 5;
    const int l  = yl & 31;
    const v4f* __restrict__ rows4 = (const v4f*)rows;
    v4f* __restrict__ out4 = (v4f*)out + (size_t)b * 9207808u + (size_t)l * LAYER4;

    const int f0 = blockIdx.x * 1024 + threadIdx.x;
#pragma unroll
    for (int u = 0; u < 2; ++u) {
        const int f = f0 + u * 512;
        int t, tstart, Asz = 16384;
        if (f < 106496) {
            if (f < 53248) { if (f < 32768) { t = 0; tstart = 0; }
                             else           { t = 1; tstart = 32768; } }
            else           { if (f < 73728) { t = 2; tstart = 53248; }
                             else           { t = 3; tstart = 73728; } }
        } else {
            if (f < 227328) { if (f < 166912) { t = 4; tstart = 106496; }
                              else            { t = 5; tstart = 166912; } }
            else            { t = 6; tstart = 227328; Asz = 44032; }
        }
        const int local = f - tstart;
        const int p = l * 7 + t;
        const v4f* __restrict__ Arow = rows4 + ((size_t)(p * 2 + b) * 2) * 256;
        v4f v;
        if (local < Asz) {
            int r = (t == 6) ? (int)(((unsigned)(local >> 6) * 1525u) >> 16)  // /43, exact x<1680
                             : (local >> 10);
            v = Arow[(r << 4) | (local & 15)];
        } else {
            int g = local - Asz;
            v = Arow[256 + ((((g >> 2) & 63) << 2) | (g & 3))];
        }
        __builtin_nontemporal_store(v, &out4[f]);
    }
}

extern "C" void kernel_launch(void* const* d_in, const int* in_sizes, int n_in,
                              void* d_out, int out_size, void* d_ws, size_t ws_size,
                              hipStream_t stream) {
    const float* cond   = (const float*)d_in[0];
    const float* Wp     = (const float*)d_in[1];
    const float* bproj  = (const float*)d_in[2];
    const float* WA1    = (const float*)d_in[3];
    const float* bA1    = (const float*)d_in[4];
    const float* WA2    = (const float*)d_in[5];
    const float* bA2    = (const float*)d_in[6];
    const float* WB1    = (const float*)d_in[7];
    const float* bB1    = (const float*)d_in[8];
    const float* WB2    = (const float*)d_in[9];
    const float* bB2    = (const float*)d_in[10];
    const float* scales = (const float*)d_in[11];
    float* out = (float*)d_out;
    float* ws  = (float*)d_ws;

    float* pe   = ws + OFF_PE;
    float* rows = ws + OFF_ROWS;

    hipLaunchKernelGGL(k_gemv,    dim3(224),     dim3(512), 0, stream, cond, Wp, bproj, pe);
    hipLaunchKernelGGL(k_dec,     dim3(112, 2),  dim3(512), 0, stream,
                       pe, WA1, bA1, WA2, bA2, WB1, bB1, WB2, bB2, scales, rows);
    hipLaunchKernelGGL(k_scatter, dim3(281, 64), dim3(512), 0, stream, rows, out);
}